// Round 3
// baseline (453.319 us; speedup 1.0000x reference)
//
#include <hip/hip_runtime.h>

#define NSTEPS 20
#define ALPHA  0.9f
#define VTH    1.0f
#define GSOMA  0.3f
#define ISCALE 0.5f

#define NOR  21
#define NORN 42
#define NLN  56
#define NPN  42
#define NKC  2000
#define NOD  34

#define TPB  256
#define KPER 8   // KCs per thread: 250 threads * 8 = 2000

__global__ __launch_bounds__(TPB)
void snn_kernel(const float* __restrict__ or_input,   // [B,21]
                const float* __restrict__ or_gains,   // [21]
                const float* __restrict__ mapping,    // [21,42]
                const float* __restrict__ orn_to_pn,  // [42,42]
                const float* __restrict__ orn_to_ln,  // [42,56]
                const float* __restrict__ ln_to_pn,   // [56,42]
                const float* __restrict__ pn_to_kc,   // [42,2000]
                const float* __restrict__ kc_to_apl,  // [2000,1]
                const float* __restrict__ apl_to_kc,  // [1,2000]
                const float* __restrict__ dec_w,      // [2000,34]
                const float* __restrict__ dec_b,      // [34]
                float* __restrict__ out)              // [B,34]
{
    __shared__ float sW_ol[NORN * NLN];   // orn_to_ln
    __shared__ float sW_op[NORN * NPN];   // orn_to_pn
    __shared__ float sW_lp[NLN * NPN];    // ln_to_pn
    __shared__ float sDrive[NORN];        // I_SCALE * orn_drive
    __shared__ float sSpg[NOR];
    __shared__ float sOrn[NORN];
    __shared__ float sLn[NLN];
    __shared__ float sApl;
    __shared__ float sRed[4];
    __shared__ float sRed2[4 * NOD];
    __shared__ unsigned long long sMask;  // PN spike bitmask

    const int tid = threadIdx.x;
    const int b   = blockIdx.x;

    // ---- stage weights into LDS ----
    for (int i = tid; i < NORN * NLN; i += TPB) sW_ol[i] = orn_to_ln[i];
    for (int i = tid; i < NORN * NPN; i += TPB) sW_op[i] = orn_to_pn[i];
    for (int i = tid; i < NLN * NPN;  i += TPB) sW_lp[i] = ln_to_pn[i];
    if (tid < NOR) sSpg[tid] = log1pf(expf(or_gains[tid]));  // softplus
    if (tid == 0)  sApl = 0.f;
    __syncthreads();

    // ---- orn_drive = (x * softplus(g)) @ mapping, pre-scaled by I_SCALE ----
    if (tid < NORN) {
        const float* x = or_input + (long)b * NOR;
        float d = 0.f;
        for (int i = 0; i < NOR; ++i) d += x[i] * sSpg[i] * mapping[i * NORN + tid];
        sDrive[tid] = d * ISCALE;
    }

    // ---- per-thread KC state (8 contiguous KCs) ----
    const int  kbase = tid * KPER;
    const bool act   = (kbase < NKC);   // tid < 250
    float vd[KPER], va[KPER], cnt[KPER], wa2k[KPER], wk2a[KPER];
#pragma unroll
    for (int j = 0; j < KPER; ++j) {
        vd[j] = 0.f; va[j] = 0.f; cnt[j] = 0.f;
        wa2k[j] = act ? apl_to_kc[kbase + j] : 0.f;
        wk2a[j] = act ? kc_to_apl[kbase + j] : 0.f;
    }
    float v_orn = 0.f, v_ln = 0.f, v_pn = 0.f, v_pn_exc = 0.f;
    __syncthreads();

    // ================= time loop =================
    for (int t = 0; t < NSTEPS; ++t) {
        // --- A: ORN LIF ---
        if (tid < NORN) {
            v_orn = ALPHA * v_orn + sDrive[tid];
            float s = (v_orn - VTH) > 0.f ? 1.f : 0.f;
            v_orn *= (1.f - s);
            sOrn[tid] = s;
        }
        __syncthreads();

        // --- B: LN (wave 0) + PN excitation (wave 1, in parallel) ---
        if (tid < NLN) {
            float a = 0.f;
            for (int o = 0; o < NORN; ++o) a += sOrn[o] * sW_ol[o * NLN + tid];
            v_ln = ALPHA * v_ln + a;
            float s = (v_ln - VTH) > 0.f ? 1.f : 0.f;
            v_ln *= (1.f - s);
            sLn[tid] = s;
        } else if (tid >= 64 && tid < 64 + NPN) {
            const int j = tid - 64;
            float a = 0.f;
            for (int o = 0; o < NORN; ++o) a += sOrn[o] * sW_op[o * NPN + j];
            v_pn_exc = a;
        }
        __syncthreads();

        // --- C: PN finish (wave 1), pack spikes into ballot mask ---
        if (tid >= 64 && tid < 64 + NPN) {
            const int j = tid - 64;
            float inh = 0.f;
            for (int l = 0; l < NLN; ++l) inh += sLn[l] * sW_lp[l * NPN + j];
            v_pn = ALPHA * v_pn + v_pn_exc - inh;
            bool s = (v_pn - VTH) > 0.f;
            if (s) v_pn = 0.f;
            unsigned long long bal = __ballot(s);   // bit j = PN j spike
            if (tid == 64) sMask = bal;
        }
        __syncthreads();

        // --- D: KC two-compartment + APL ---
        {
            const float apl = sApl;
#pragma unroll
            for (int j = 0; j < KPER; ++j) vd[j] = ALPHA * vd[j] - apl * wa2k[j];

            // gather over spiking PNs, 8 rows per batch: issue all 16 float4
            // loads before any use -> one latency exposure per batch instead
            // of per row.
            unsigned long long m = sMask;  // wave-uniform
            while (m) {
                int   p[8];
                float f[8];
                p[0] = __builtin_ctzll(m); m &= m - 1; f[0] = 1.f;
#pragma unroll
                for (int q = 1; q < 8; ++q) {
                    if (m) { p[q] = __builtin_ctzll(m); m &= m - 1; f[q] = 1.f; }
                    else   { p[q] = p[0];               f[q] = 0.f; }
                }
                if (act) {
                    float4 lo[8], hi[8];
#pragma unroll
                    for (int q = 0; q < 8; ++q) {
                        const float4* w = (const float4*)(pn_to_kc + (long)p[q] * NKC + kbase);
                        lo[q] = w[0];
                        hi[q] = w[1];
                    }
#pragma unroll
                    for (int q = 0; q < 8; ++q) {
                        vd[0] += f[q] * lo[q].x;
                        vd[1] += f[q] * lo[q].y;
                        vd[2] += f[q] * lo[q].z;
                        vd[3] += f[q] * lo[q].w;
                        vd[4] += f[q] * hi[q].x;
                        vd[5] += f[q] * hi[q].y;
                        vd[6] += f[q] * hi[q].z;
                        vd[7] += f[q] * hi[q].w;
                    }
                }
            }

            float aplp = 0.f;
#pragma unroll
            for (int j = 0; j < KPER; ++j) {
                va[j] = ALPHA * va[j] + GSOMA * (vd[j] - va[j]);
                float s = (va[j] - VTH) > 0.f ? 1.f : 0.f;
                va[j] *= (1.f - s);
                cnt[j] += s;
                aplp += s * wk2a[j];
            }
            // block reduction of APL drive
            for (int off = 32; off > 0; off >>= 1) aplp += __shfl_xor(aplp, off, 64);
            if ((tid & 63) == 0) sRed[tid >> 6] = aplp;
        }
        __syncthreads();
        if (tid == 0) {
            float a = sRed[0] + sRed[1] + sRed[2] + sRed[3];
            sApl = fmaxf(a, 0.f);   // relu, APL_GAIN = 1
        }
        // sApl consumed in stage D next step; barriers A-C order the access.
    }

    // ================= epilogue: logits = (cnt/20) @ dec_w + dec_b =================
    float acc[NOD];
#pragma unroll
    for (int o = 0; o < NOD; ++o) acc[o] = 0.f;
    if (act) {
#pragma unroll
        for (int j = 0; j < KPER; ++j) {
            float r = cnt[j] / 20.0f;
            if (r != 0.f) {                       // KC sparsity: skip silent KCs
                const float* wr = dec_w + (long)(kbase + j) * NOD;
#pragma unroll
                for (int o = 0; o < NOD; ++o) acc[o] += r * wr[o];
            }
        }
    }
#pragma unroll
    for (int o = 0; o < NOD; ++o) {
        float v = acc[o];
        for (int off = 32; off > 0; off >>= 1) v += __shfl_xor(v, off, 64);
        if ((tid & 63) == 0) sRed2[(tid >> 6) * NOD + o] = v;
    }
    __syncthreads();
    if (tid < NOD) {
        float v = sRed2[tid] + sRed2[NOD + tid] + sRed2[2 * NOD + tid] +
                  sRed2[3 * NOD + tid] + dec_b[tid];
        out[(long)b * NOD + tid] = v;
    }
}

extern "C" void kernel_launch(void* const* d_in, const int* in_sizes, int n_in,
                              void* d_out, int out_size, void* d_ws, size_t ws_size,
                              hipStream_t stream) {
    (void)n_in; (void)out_size; (void)d_ws; (void)ws_size;
    const float* or_input  = (const float*)d_in[0];
    const float* or_gains  = (const float*)d_in[1];
    const float* mapping   = (const float*)d_in[2];
    const float* orn_to_pn = (const float*)d_in[3];
    const float* orn_to_ln = (const float*)d_in[4];
    const float* ln_to_pn  = (const float*)d_in[5];
    const float* pn_to_kc  = (const float*)d_in[6];
    const float* kc_to_apl = (const float*)d_in[7];
    const float* apl_to_kc = (const float*)d_in[8];
    const float* dec_w     = (const float*)d_in[9];
    const float* dec_b     = (const float*)d_in[10];
    float* out = (float*)d_out;

    const int batch = in_sizes[0] / NOR;  // 4096
    hipLaunchKernelGGL(snn_kernel, dim3(batch), dim3(TPB), 0, stream,
                       or_input, or_gains, mapping, orn_to_pn, orn_to_ln,
                       ln_to_pn, pn_to_kc, kc_to_apl, apl_to_kc, dec_w, dec_b, out);
}

// Round 4
// 245.534 us; speedup vs baseline: 1.8463x; 1.8463x over previous
//
#include <hip/hip_runtime.h>

#define NSTEPS 20
#define ALPHA  0.9f
#define VTH    1.0f
#define GSOMA  0.3f
#define ISCALE 0.5f

#define NOR  21
#define NORN 42
#define NLN  56
#define NPN  42
#define NKC  2000
#define NOD  34

#define TPB  256
#define KPER 8   // KCs per thread: 250 threads * 8 = 2000

// ===================== Phase 1: small net -> PN spike masks =====================
// One wave per batch row, 4 rows per block, no barriers after staging.
// Sparse ctz-loops skip exact-zero spike terms -> bit-identical to dense sum.
__global__ __launch_bounds__(TPB)
void phase1_kernel(const float* __restrict__ or_input,   // [B,21]
                   const float* __restrict__ or_gains,   // [21]
                   const float* __restrict__ mapping,    // [21,42]
                   const float* __restrict__ orn_to_pn,  // [42,42]
                   const float* __restrict__ orn_to_ln,  // [42,56]
                   const float* __restrict__ ln_to_pn,   // [56,42]
                   unsigned long long* __restrict__ g_masks, // [B,20]
                   int batch)
{
    __shared__ float sW_ol[NORN * NLN];
    __shared__ float sW_op[NORN * NPN];
    __shared__ float sW_lp[NLN * NPN];
    __shared__ float sMap[NOR * NORN];
    __shared__ float sSpg[NOR];

    const int tid  = threadIdx.x;
    const int lane = tid & 63;
    const int wid  = tid >> 6;

    for (int i = tid; i < NORN * NLN; i += TPB) sW_ol[i] = orn_to_ln[i];
    for (int i = tid; i < NORN * NPN; i += TPB) sW_op[i] = orn_to_pn[i];
    for (int i = tid; i < NLN * NPN;  i += TPB) sW_lp[i] = ln_to_pn[i];
    for (int i = tid; i < NOR * NORN; i += TPB) sMap[i]  = mapping[i];
    if (tid < NOR) sSpg[tid] = log1pf(expf(or_gains[tid]));  // softplus
    __syncthreads();

    const int row = blockIdx.x * 4 + wid;
    if (row >= batch) return;   // no barriers below

    // drive: same association order as reference: (x * spg) * map, ascending i
    float drive = 0.f;
    if (lane < NORN) {
        const float* x = or_input + (long)row * NOR;
        for (int i = 0; i < NOR; ++i) drive += x[i] * sSpg[i] * sMap[i * NORN + lane];
        drive *= ISCALE;
    }

    float v_orn = 0.f, v_ln = 0.f, v_pn = 0.f;
    unsigned long long* outm = g_masks + (long)row * NSTEPS;

    for (int t = 0; t < NSTEPS; ++t) {
        bool so = false;
        if (lane < NORN) {
            v_orn = ALPHA * v_orn + drive;
            so = (v_orn - VTH) > 0.f;
            if (so) v_orn = 0.f;
        }
        unsigned long long mOrn = __ballot(so);

        bool sl = false;
        if (lane < NLN) {
            float a = 0.f;
            unsigned long long m = mOrn;           // wave-uniform, ascending bits
            while (m) {
                int o = __builtin_ctzll(m); m &= m - 1;
                a += sW_ol[o * NLN + lane];
            }
            v_ln = ALPHA * v_ln + a;
            sl = (v_ln - VTH) > 0.f;
            if (sl) v_ln = 0.f;
        }
        unsigned long long mLn = __ballot(sl);

        bool sp = false;
        if (lane < NPN) {
            float e = 0.f;
            unsigned long long m = mOrn;
            while (m) {
                int o = __builtin_ctzll(m); m &= m - 1;
                e += sW_op[o * NPN + lane];
            }
            float h = 0.f;
            m = mLn;
            while (m) {
                int l = __builtin_ctzll(m); m &= m - 1;
                h += sW_lp[l * NPN + lane];
            }
            v_pn = ALPHA * v_pn + e - h;
            sp = (v_pn - VTH) > 0.f;
            if (sp) v_pn = 0.f;
        }
        unsigned long long mPn = __ballot(sp);
        if (lane == 0) outm[t] = mPn;
    }
}

// ===================== Phase 2: KC two-compartment + APL + logits =====================
// One block per row; no weight LDS (only APL partials) -> 8 blocks/CU resident.
// One barrier per step via double-buffered partials. Numerics identical to R1 stage D.
__global__ __launch_bounds__(TPB)
void phase2_kernel(const unsigned long long* __restrict__ g_masks, // [B,20]
                   const float* __restrict__ pn_to_kc,  // [42,2000]
                   const float* __restrict__ kc_to_apl, // [2000,1]
                   const float* __restrict__ apl_to_kc, // [1,2000]
                   const float* __restrict__ dec_w,     // [2000,34]
                   const float* __restrict__ dec_b,     // [34]
                   float* __restrict__ out)             // [B,34]
{
    __shared__ float sRed[2][4];
    __shared__ float sRed2[4 * NOD];

    const int tid  = threadIdx.x;
    const int lane = tid & 63;
    const int wid  = tid >> 6;
    const int b    = blockIdx.x;

    const int  kbase = tid * KPER;
    const bool act   = (kbase < NKC);   // tid < 250
    float vd[KPER], va[KPER], cnt[KPER], wa2k[KPER], wk2a[KPER];
#pragma unroll
    for (int j = 0; j < KPER; ++j) {
        vd[j] = 0.f; va[j] = 0.f; cnt[j] = 0.f;
        wa2k[j] = act ? apl_to_kc[kbase + j] : 0.f;
        wk2a[j] = act ? kc_to_apl[kbase + j] : 0.f;
    }
    if (tid < 8) sRed[tid >> 2][tid & 3] = 0.f;   // zero both buffers
    __syncthreads();

    const unsigned long long* gm = g_masks + (long)b * NSTEPS;

    for (int t = 0; t < NSTEPS; ++t) {
        // APL from previous step's partials (buffer (t+1)&1; zeros at t=0)
        const float* rp = sRed[(t + 1) & 1];
        const float apl = fmaxf(rp[0] + rp[1] + rp[2] + rp[3], 0.f);

#pragma unroll
        for (int j = 0; j < KPER; ++j) vd[j] = ALPHA * vd[j] - apl * wa2k[j];

        unsigned long long m = gm[t];   // wave-uniform scalar load
        while (m) {
            const int p = __builtin_ctzll(m);
            m &= m - 1;
            if (act) {
                const float4* w = (const float4*)(pn_to_kc + (long)p * NKC + kbase);
                float4 w0 = w[0], w1 = w[1];
                vd[0] += w0.x; vd[1] += w0.y; vd[2] += w0.z; vd[3] += w0.w;
                vd[4] += w1.x; vd[5] += w1.y; vd[6] += w1.z; vd[7] += w1.w;
            }
        }

        float aplp = 0.f;
#pragma unroll
        for (int j = 0; j < KPER; ++j) {
            va[j] = ALPHA * va[j] + GSOMA * (vd[j] - va[j]);
            float s = (va[j] - VTH) > 0.f ? 1.f : 0.f;
            va[j] *= (1.f - s);
            cnt[j] += s;
            aplp += s * wk2a[j];
        }
        for (int off = 32; off > 0; off >>= 1) aplp += __shfl_xor(aplp, off, 64);
        if (lane == 0) sRed[t & 1][wid] = aplp;
        __syncthreads();   // partials visible for t+1; prev buffer free for t+2
    }

    // ---- epilogue: logits = (cnt/20) @ dec_w + dec_b ----
    float acc[NOD];
#pragma unroll
    for (int o = 0; o < NOD; ++o) acc[o] = 0.f;
    if (act) {
#pragma unroll
        for (int j = 0; j < KPER; ++j) {
            float r = cnt[j] / 20.0f;
            if (r != 0.f) {
                const float* wr = dec_w + (long)(kbase + j) * NOD;
#pragma unroll
                for (int o = 0; o < NOD; ++o) acc[o] += r * wr[o];
            }
        }
    }
#pragma unroll
    for (int o = 0; o < NOD; ++o) {
        float v = acc[o];
        for (int off = 32; off > 0; off >>= 1) v += __shfl_xor(v, off, 64);
        if (lane == 0) sRed2[wid * NOD + o] = v;
    }
    __syncthreads();
    if (tid < NOD) {
        float v = sRed2[tid] + sRed2[NOD + tid] + sRed2[2 * NOD + tid] +
                  sRed2[3 * NOD + tid] + dec_b[tid];
        out[(long)b * NOD + tid] = v;
    }
}

// ===================== Fallback: round-1 fused kernel (proven) =====================
__global__ __launch_bounds__(TPB)
void snn_fused(const float* __restrict__ or_input, const float* __restrict__ or_gains,
               const float* __restrict__ mapping, const float* __restrict__ orn_to_pn,
               const float* __restrict__ orn_to_ln, const float* __restrict__ ln_to_pn,
               const float* __restrict__ pn_to_kc, const float* __restrict__ kc_to_apl,
               const float* __restrict__ apl_to_kc, const float* __restrict__ dec_w,
               const float* __restrict__ dec_b, float* __restrict__ out)
{
    __shared__ float sW_ol[NORN * NLN];
    __shared__ float sW_op[NORN * NPN];
    __shared__ float sW_lp[NLN * NPN];
    __shared__ float sDrive[NORN];
    __shared__ float sSpg[NOR];
    __shared__ float sOrn[NORN];
    __shared__ float sLn[NLN];
    __shared__ float sApl;
    __shared__ float sRed[4];
    __shared__ float sRed2[4 * NOD];
    __shared__ unsigned long long sMask;

    const int tid = threadIdx.x;
    const int b   = blockIdx.x;

    for (int i = tid; i < NORN * NLN; i += TPB) sW_ol[i] = orn_to_ln[i];
    for (int i = tid; i < NORN * NPN; i += TPB) sW_op[i] = orn_to_pn[i];
    for (int i = tid; i < NLN * NPN;  i += TPB) sW_lp[i] = ln_to_pn[i];
    if (tid < NOR) sSpg[tid] = log1pf(expf(or_gains[tid]));
    if (tid == 0)  sApl = 0.f;
    __syncthreads();

    if (tid < NORN) {
        const float* x = or_input + (long)b * NOR;
        float d = 0.f;
        for (int i = 0; i < NOR; ++i) d += x[i] * sSpg[i] * mapping[i * NORN + tid];
        sDrive[tid] = d * ISCALE;
    }

    const int  kbase = tid * KPER;
    const bool act   = (kbase < NKC);
    float vd[KPER], va[KPER], cnt[KPER], wa2k[KPER], wk2a[KPER];
#pragma unroll
    for (int j = 0; j < KPER; ++j) {
        vd[j] = 0.f; va[j] = 0.f; cnt[j] = 0.f;
        wa2k[j] = act ? apl_to_kc[kbase + j] : 0.f;
        wk2a[j] = act ? kc_to_apl[kbase + j] : 0.f;
    }
    float v_orn = 0.f, v_ln = 0.f, v_pn = 0.f, v_pn_exc = 0.f;
    __syncthreads();

    for (int t = 0; t < NSTEPS; ++t) {
        if (tid < NORN) {
            v_orn = ALPHA * v_orn + sDrive[tid];
            float s = (v_orn - VTH) > 0.f ? 1.f : 0.f;
            v_orn *= (1.f - s);
            sOrn[tid] = s;
        }
        __syncthreads();
        if (tid < NLN) {
            float a = 0.f;
            for (int o = 0; o < NORN; ++o) a += sOrn[o] * sW_ol[o * NLN + tid];
            v_ln = ALPHA * v_ln + a;
            float s = (v_ln - VTH) > 0.f ? 1.f : 0.f;
            v_ln *= (1.f - s);
            sLn[tid] = s;
        } else if (tid >= 64 && tid < 64 + NPN) {
            const int j = tid - 64;
            float a = 0.f;
            for (int o = 0; o < NORN; ++o) a += sOrn[o] * sW_op[o * NPN + j];
            v_pn_exc = a;
        }
        __syncthreads();
        if (tid >= 64 && tid < 64 + NPN) {
            const int j = tid - 64;
            float inh = 0.f;
            for (int l = 0; l < NLN; ++l) inh += sLn[l] * sW_lp[l * NPN + j];
            v_pn = ALPHA * v_pn + v_pn_exc - inh;
            bool s = (v_pn - VTH) > 0.f;
            if (s) v_pn = 0.f;
            unsigned long long bal = __ballot(s);
            if (tid == 64) sMask = bal;
        }
        __syncthreads();
        {
            const float apl = sApl;
#pragma unroll
            for (int j = 0; j < KPER; ++j) vd[j] = ALPHA * vd[j] - apl * wa2k[j];
            unsigned long long m = sMask;
            while (m) {
                const int p = __builtin_ctzll(m);
                m &= m - 1;
                if (act) {
                    const float4* w = (const float4*)(pn_to_kc + (long)p * NKC + kbase);
                    float4 w0 = w[0], w1 = w[1];
                    vd[0] += w0.x; vd[1] += w0.y; vd[2] += w0.z; vd[3] += w0.w;
                    vd[4] += w1.x; vd[5] += w1.y; vd[6] += w1.z; vd[7] += w1.w;
                }
            }
            float aplp = 0.f;
#pragma unroll
            for (int j = 0; j < KPER; ++j) {
                va[j] = ALPHA * va[j] + GSOMA * (vd[j] - va[j]);
                float s = (va[j] - VTH) > 0.f ? 1.f : 0.f;
                va[j] *= (1.f - s);
                cnt[j] += s;
                aplp += s * wk2a[j];
            }
            for (int off = 32; off > 0; off >>= 1) aplp += __shfl_xor(aplp, off, 64);
            if ((tid & 63) == 0) sRed[tid >> 6] = aplp;
        }
        __syncthreads();
        if (tid == 0) {
            float a = sRed[0] + sRed[1] + sRed[2] + sRed[3];
            sApl = fmaxf(a, 0.f);
        }
    }

    float acc[NOD];
#pragma unroll
    for (int o = 0; o < NOD; ++o) acc[o] = 0.f;
    if (act) {
#pragma unroll
        for (int j = 0; j < KPER; ++j) {
            float r = cnt[j] / 20.0f;
            if (r != 0.f) {
                const float* wr = dec_w + (long)(kbase + j) * NOD;
#pragma unroll
                for (int o = 0; o < NOD; ++o) acc[o] += r * wr[o];
            }
        }
    }
#pragma unroll
    for (int o = 0; o < NOD; ++o) {
        float v = acc[o];
        for (int off = 32; off > 0; off >>= 1) v += __shfl_xor(v, off, 64);
        if ((tid & 63) == 0) sRed2[(tid >> 6) * NOD + o] = v;
    }
    __syncthreads();
    if (tid < NOD) {
        float v = sRed2[tid] + sRed2[NOD + tid] + sRed2[2 * NOD + tid] +
                  sRed2[3 * NOD + tid] + dec_b[tid];
        out[(long)b * NOD + tid] = v;
    }
}

extern "C" void kernel_launch(void* const* d_in, const int* in_sizes, int n_in,
                              void* d_out, int out_size, void* d_ws, size_t ws_size,
                              hipStream_t stream) {
    (void)n_in; (void)out_size;
    const float* or_input  = (const float*)d_in[0];
    const float* or_gains  = (const float*)d_in[1];
    const float* mapping   = (const float*)d_in[2];
    const float* orn_to_pn = (const float*)d_in[3];
    const float* orn_to_ln = (const float*)d_in[4];
    const float* ln_to_pn  = (const float*)d_in[5];
    const float* pn_to_kc  = (const float*)d_in[6];
    const float* kc_to_apl = (const float*)d_in[7];
    const float* apl_to_kc = (const float*)d_in[8];
    const float* dec_w     = (const float*)d_in[9];
    const float* dec_b     = (const float*)d_in[10];
    float* out = (float*)d_out;

    const int batch = in_sizes[0] / NOR;  // 4096
    const size_t need = (size_t)batch * NSTEPS * sizeof(unsigned long long);

    if (ws_size >= need) {
        unsigned long long* g_masks = (unsigned long long*)d_ws;
        hipLaunchKernelGGL(phase1_kernel, dim3((batch + 3) / 4), dim3(TPB), 0, stream,
                           or_input, or_gains, mapping, orn_to_pn, orn_to_ln, ln_to_pn,
                           g_masks, batch);
        hipLaunchKernelGGL(phase2_kernel, dim3(batch), dim3(TPB), 0, stream,
                           g_masks, pn_to_kc, kc_to_apl, apl_to_kc, dec_w, dec_b, out);
    } else {
        hipLaunchKernelGGL(snn_fused, dim3(batch), dim3(TPB), 0, stream,
                           or_input, or_gains, mapping, orn_to_pn, orn_to_ln,
                           ln_to_pn, pn_to_kc, kc_to_apl, apl_to_kc, dec_w, dec_b, out);
    }
}

// Round 5
// 237.071 us; speedup vs baseline: 1.9122x; 1.0357x over previous
//
#include <hip/hip_runtime.h>

#define NSTEPS 20
#define ALPHA  0.9f
#define VTH    1.0f
#define GSOMA  0.3f
#define ISCALE 0.5f

#define NOR  21
#define NORN 42
#define NLN  56
#define NPN  42
#define NKC  2000
#define NOD  34

#define TPB  256
#define KPER 8   // KCs per thread: 250 threads * 8 = 2000

// ===================== Phase 1: small net -> PN spike masks =====================
// One wave per batch row, 4 rows per block, no barriers after staging.
// LDS gathers batched 4 bits at a time (loads pipelined), accumulation kept
// strictly sequential in ascending bit order -> bit-identical to dense sum.
// Arrays padded +24 so lanes beyond the layer width read in-bounds garbage
// (their results are never used).
__global__ __launch_bounds__(TPB)
void phase1_kernel(const float* __restrict__ or_input,   // [B,21]
                   const float* __restrict__ or_gains,   // [21]
                   const float* __restrict__ mapping,    // [21,42]
                   const float* __restrict__ orn_to_pn,  // [42,42]
                   const float* __restrict__ orn_to_ln,  // [42,56]
                   const float* __restrict__ ln_to_pn,   // [56,42]
                   unsigned long long* __restrict__ g_masks, // [B,20]
                   int batch)
{
    __shared__ float sW_ol[NORN * NLN + 24];
    __shared__ float sW_op[NORN * NPN + 24];
    __shared__ float sW_lp[NLN * NPN + 24];
    __shared__ float sSpg[NOR];

    const int tid  = threadIdx.x;
    const int lane = tid & 63;
    const int wid  = tid >> 6;

    for (int i = tid; i < NORN * NLN; i += TPB) sW_ol[i] = orn_to_ln[i];
    for (int i = tid; i < NORN * NPN; i += TPB) sW_op[i] = orn_to_pn[i];
    for (int i = tid; i < NLN * NPN;  i += TPB) sW_lp[i] = ln_to_pn[i];
    if (tid < NOR) sSpg[tid] = log1pf(expf(or_gains[tid]));  // softplus
    __syncthreads();

    const int row = blockIdx.x * 4 + wid;
    if (row >= batch) return;   // no barriers below

    // drive: same association order as reference: sum_i (x_i*spg_i)*map[i][lane]
    float drive = 0.f;
    if (lane < NORN) {
        const float* x = or_input + (long)row * NOR;
        for (int i = 0; i < NOR; ++i) drive += x[i] * sSpg[i] * mapping[i * NORN + lane];
        drive *= ISCALE;
    }

    float v_orn = 0.f, v_ln = 0.f, v_pn = 0.f;
    unsigned long long* outm = g_masks + (long)row * NSTEPS;

    for (int t = 0; t < NSTEPS; ++t) {
        // --- ORN LIF (VALU only) ---
        bool so = false;
        if (lane < NORN) {
            v_orn = ALPHA * v_orn + drive;
            so = (v_orn - VTH) > 0.f;
            if (so) v_orn = 0.f;
        }
        const unsigned long long mOrn = __ballot(so);

        // --- fused gather over mOrn: LN input and PN excitation, 4 bits/batch ---
        float aln = 0.f, apn = 0.f;
        {
            unsigned long long m = mOrn;
            while (m) {
                int o0 = __builtin_ctzll(m); m &= m - 1;
                int o1 = o0, o2 = o0, o3 = o0;
                float f1 = 0.f, f2 = 0.f, f3 = 0.f;
                if (m) { o1 = __builtin_ctzll(m); m &= m - 1; f1 = 1.f; }
                if (m) { o2 = __builtin_ctzll(m); m &= m - 1; f2 = 1.f; }
                if (m) { o3 = __builtin_ctzll(m); m &= m - 1; f3 = 1.f; }
                // issue all 8 LDS loads before any use
                float l0 = sW_ol[o0 * NLN + lane];
                float l1 = sW_ol[o1 * NLN + lane];
                float l2 = sW_ol[o2 * NLN + lane];
                float l3 = sW_ol[o3 * NLN + lane];
                float p0 = sW_op[o0 * NPN + lane];
                float p1 = sW_op[o1 * NPN + lane];
                float p2 = sW_op[o2 * NPN + lane];
                float p3 = sW_op[o3 * NPN + lane];
                // strictly sequential accumulation, ascending bits (exact)
                aln += l0; aln += f1 * l1; aln += f2 * l2; aln += f3 * l3;
                apn += p0; apn += f1 * p1; apn += f2 * p2; apn += f3 * p3;
            }
        }

        // --- LN LIF ---
        bool sl = false;
        if (lane < NLN) {
            v_ln = ALPHA * v_ln + aln;
            sl = (v_ln - VTH) > 0.f;
            if (sl) v_ln = 0.f;
        }
        const unsigned long long mLn = __ballot(sl);

        // --- PN inhibition gather over mLn, 4 bits/batch ---
        float h = 0.f;
        {
            unsigned long long m = mLn;
            while (m) {
                int l0i = __builtin_ctzll(m); m &= m - 1;
                int l1i = l0i, l2i = l0i, l3i = l0i;
                float f1 = 0.f, f2 = 0.f, f3 = 0.f;
                if (m) { l1i = __builtin_ctzll(m); m &= m - 1; f1 = 1.f; }
                if (m) { l2i = __builtin_ctzll(m); m &= m - 1; f2 = 1.f; }
                if (m) { l3i = __builtin_ctzll(m); m &= m - 1; f3 = 1.f; }
                float w0 = sW_lp[l0i * NPN + lane];
                float w1 = sW_lp[l1i * NPN + lane];
                float w2 = sW_lp[l2i * NPN + lane];
                float w3 = sW_lp[l3i * NPN + lane];
                h += w0; h += f1 * w1; h += f2 * w2; h += f3 * w3;
            }
        }

        // --- PN LIF ---
        bool sp = false;
        if (lane < NPN) {
            v_pn = ALPHA * v_pn + apn - h;
            sp = (v_pn - VTH) > 0.f;
            if (sp) v_pn = 0.f;
        }
        const unsigned long long mPn = __ballot(sp);
        if (lane == 0) outm[t] = mPn;
    }
}

// ===================== Phase 2: KC two-compartment + APL + logits =====================
// One block per row; tiny LDS -> many blocks/CU. One barrier per step via
// double-buffered APL partials. Gather batched 2 PN rows (4 float4 in flight),
// accumulation sequential in ascending PN order (exact).
__global__ __launch_bounds__(TPB)
void phase2_kernel(const unsigned long long* __restrict__ g_masks, // [B,20]
                   const float* __restrict__ pn_to_kc,  // [42,2000]
                   const float* __restrict__ kc_to_apl, // [2000,1]
                   const float* __restrict__ apl_to_kc, // [1,2000]
                   const float* __restrict__ dec_w,     // [2000,34]
                   const float* __restrict__ dec_b,     // [34]
                   float* __restrict__ out)             // [B,34]
{
    __shared__ float sRed[2][4];
    __shared__ float sRed2[4 * NOD];

    const int tid  = threadIdx.x;
    const int lane = tid & 63;
    const int wid  = tid >> 6;
    const int b    = blockIdx.x;

    const int  kbase = tid * KPER;
    const bool act   = (kbase < NKC);   // tid < 250
    float vd[KPER], va[KPER], cnt[KPER], wa2k[KPER], wk2a[KPER];
#pragma unroll
    for (int j = 0; j < KPER; ++j) { vd[j] = 0.f; va[j] = 0.f; cnt[j] = 0.f; }
    {
        // vectorized weight staging (kbase is 32B-aligned)
        const float4* a4 = (const float4*)(apl_to_kc + (act ? kbase : 0));
        const float4* k4 = (const float4*)(kc_to_apl + (act ? kbase : 0));
        float4 a0 = a4[0], a1 = a4[1], k0 = k4[0], k1 = k4[1];
        const float g = act ? 1.f : 0.f;
        wa2k[0] = g * a0.x; wa2k[1] = g * a0.y; wa2k[2] = g * a0.z; wa2k[3] = g * a0.w;
        wa2k[4] = g * a1.x; wa2k[5] = g * a1.y; wa2k[6] = g * a1.z; wa2k[7] = g * a1.w;
        wk2a[0] = g * k0.x; wk2a[1] = g * k0.y; wk2a[2] = g * k0.z; wk2a[3] = g * k0.w;
        wk2a[4] = g * k1.x; wk2a[5] = g * k1.y; wk2a[6] = g * k1.z; wk2a[7] = g * k1.w;
    }
    if (tid < 8) sRed[tid >> 2][tid & 3] = 0.f;   // zero both buffers
    __syncthreads();

    const unsigned long long* gm = g_masks + (long)b * NSTEPS;

    for (int t = 0; t < NSTEPS; ++t) {
        // APL from previous step's partials (buffer (t+1)&1; zeros at t=0)
        const float* rp = sRed[(t + 1) & 1];
        const float apl = fmaxf(rp[0] + rp[1] + rp[2] + rp[3], 0.f);

#pragma unroll
        for (int j = 0; j < KPER; ++j) vd[j] = ALPHA * vd[j] - apl * wa2k[j];

        // gather over spiking PNs: 2 rows per batch, 4 float4 loads in flight
        unsigned long long m = gm[t];   // wave-uniform scalar load
        while (m) {
            const int p0 = __builtin_ctzll(m); m &= m - 1;
            int p1 = p0; float f1 = 0.f;
            if (m) { p1 = __builtin_ctzll(m); m &= m - 1; f1 = 1.f; }
            if (act) {
                const float4* w0 = (const float4*)(pn_to_kc + (long)p0 * NKC + kbase);
                const float4* w1 = (const float4*)(pn_to_kc + (long)p1 * NKC + kbase);
                float4 a0 = w0[0], a1 = w0[1];
                float4 b0 = w1[0], b1 = w1[1];
                // row p0 first, then p1 (ascending) -- sequential, exact
                vd[0] += a0.x; vd[1] += a0.y; vd[2] += a0.z; vd[3] += a0.w;
                vd[4] += a1.x; vd[5] += a1.y; vd[6] += a1.z; vd[7] += a1.w;
                vd[0] += f1 * b0.x; vd[1] += f1 * b0.y; vd[2] += f1 * b0.z; vd[3] += f1 * b0.w;
                vd[4] += f1 * b1.x; vd[5] += f1 * b1.y; vd[6] += f1 * b1.z; vd[7] += f1 * b1.w;
            }
        }

        float aplp = 0.f;
#pragma unroll
        for (int j = 0; j < KPER; ++j) {
            va[j] = ALPHA * va[j] + GSOMA * (vd[j] - va[j]);
            float s = (va[j] - VTH) > 0.f ? 1.f : 0.f;
            va[j] *= (1.f - s);
            cnt[j] += s;
            aplp += s * wk2a[j];
        }
        for (int off = 32; off > 0; off >>= 1) aplp += __shfl_xor(aplp, off, 64);
        if (lane == 0) sRed[t & 1][wid] = aplp;
        __syncthreads();   // partials visible for t+1; prev buffer free for t+2
    }

    // ---- epilogue: logits = (cnt/20) @ dec_w + dec_b ----
    float acc[NOD];
#pragma unroll
    for (int o = 0; o < NOD; ++o) acc[o] = 0.f;
    if (act) {
#pragma unroll
        for (int j = 0; j < KPER; ++j) {
            float r = cnt[j] / 20.0f;
            if (r != 0.f) {
                const float* wr = dec_w + (long)(kbase + j) * NOD;
#pragma unroll
                for (int o = 0; o < NOD; ++o) acc[o] += r * wr[o];
            }
        }
    }
#pragma unroll
    for (int o = 0; o < NOD; ++o) {
        float v = acc[o];
        for (int off = 32; off > 0; off >>= 1) v += __shfl_xor(v, off, 64);
        if (lane == 0) sRed2[wid * NOD + o] = v;
    }
    __syncthreads();
    if (tid < NOD) {
        float v = sRed2[tid] + sRed2[NOD + tid] + sRed2[2 * NOD + tid] +
                  sRed2[3 * NOD + tid] + dec_b[tid];
        out[(long)b * NOD + tid] = v;
    }
}

// ===================== Fallback: round-1 fused kernel (proven) =====================
__global__ __launch_bounds__(TPB)
void snn_fused(const float* __restrict__ or_input, const float* __restrict__ or_gains,
               const float* __restrict__ mapping, const float* __restrict__ orn_to_pn,
               const float* __restrict__ orn_to_ln, const float* __restrict__ ln_to_pn,
               const float* __restrict__ pn_to_kc, const float* __restrict__ kc_to_apl,
               const float* __restrict__ apl_to_kc, const float* __restrict__ dec_w,
               const float* __restrict__ dec_b, float* __restrict__ out)
{
    __shared__ float sW_ol[NORN * NLN];
    __shared__ float sW_op[NORN * NPN];
    __shared__ float sW_lp[NLN * NPN];
    __shared__ float sDrive[NORN];
    __shared__ float sSpg[NOR];
    __shared__ float sOrn[NORN];
    __shared__ float sLn[NLN];
    __shared__ float sApl;
    __shared__ float sRed[4];
    __shared__ float sRed2[4 * NOD];
    __shared__ unsigned long long sMask;

    const int tid = threadIdx.x;
    const int b   = blockIdx.x;

    for (int i = tid; i < NORN * NLN; i += TPB) sW_ol[i] = orn_to_ln[i];
    for (int i = tid; i < NORN * NPN; i += TPB) sW_op[i] = orn_to_pn[i];
    for (int i = tid; i < NLN * NPN;  i += TPB) sW_lp[i] = ln_to_pn[i];
    if (tid < NOR) sSpg[tid] = log1pf(expf(or_gains[tid]));
    if (tid == 0)  sApl = 0.f;
    __syncthreads();

    if (tid < NORN) {
        const float* x = or_input + (long)b * NOR;
        float d = 0.f;
        for (int i = 0; i < NOR; ++i) d += x[i] * sSpg[i] * mapping[i * NORN + tid];
        sDrive[tid] = d * ISCALE;
    }

    const int  kbase = tid * KPER;
    const bool act   = (kbase < NKC);
    float vd[KPER], va[KPER], cnt[KPER], wa2k[KPER], wk2a[KPER];
#pragma unroll
    for (int j = 0; j < KPER; ++j) {
        vd[j] = 0.f; va[j] = 0.f; cnt[j] = 0.f;
        wa2k[j] = act ? apl_to_kc[kbase + j] : 0.f;
        wk2a[j] = act ? kc_to_apl[kbase + j] : 0.f;
    }
    float v_orn = 0.f, v_ln = 0.f, v_pn = 0.f, v_pn_exc = 0.f;
    __syncthreads();

    for (int t = 0; t < NSTEPS; ++t) {
        if (tid < NORN) {
            v_orn = ALPHA * v_orn + sDrive[tid];
            float s = (v_orn - VTH) > 0.f ? 1.f : 0.f;
            v_orn *= (1.f - s);
            sOrn[tid] = s;
        }
        __syncthreads();
        if (tid < NLN) {
            float a = 0.f;
            for (int o = 0; o < NORN; ++o) a += sOrn[o] * sW_ol[o * NLN + tid];
            v_ln = ALPHA * v_ln + a;
            float s = (v_ln - VTH) > 0.f ? 1.f : 0.f;
            v_ln *= (1.f - s);
            sLn[tid] = s;
        } else if (tid >= 64 && tid < 64 + NPN) {
            const int j = tid - 64;
            float a = 0.f;
            for (int o = 0; o < NORN; ++o) a += sOrn[o] * sW_op[o * NPN + j];
            v_pn_exc = a;
        }
        __syncthreads();
        if (tid >= 64 && tid < 64 + NPN) {
            const int j = tid - 64;
            float inh = 0.f;
            for (int l = 0; l < NLN; ++l) inh += sLn[l] * sW_lp[l * NPN + j];
            v_pn = ALPHA * v_pn + v_pn_exc - inh;
            bool s = (v_pn - VTH) > 0.f;
            if (s) v_pn = 0.f;
            unsigned long long bal = __ballot(s);
            if (tid == 64) sMask = bal;
        }
        __syncthreads();
        {
            const float apl = sApl;
#pragma unroll
            for (int j = 0; j < KPER; ++j) vd[j] = ALPHA * vd[j] - apl * wa2k[j];
            unsigned long long m = sMask;
            while (m) {
                const int p = __builtin_ctzll(m);
                m &= m - 1;
                if (act) {
                    const float4* w = (const float4*)(pn_to_kc + (long)p * NKC + kbase);
                    float4 w0 = w[0], w1 = w[1];
                    vd[0] += w0.x; vd[1] += w0.y; vd[2] += w0.z; vd[3] += w0.w;
                    vd[4] += w1.x; vd[5] += w1.y; vd[6] += w1.z; vd[7] += w1.w;
                }
            }
            float aplp = 0.f;
#pragma unroll
            for (int j = 0; j < KPER; ++j) {
                va[j] = ALPHA * va[j] + GSOMA * (vd[j] - va[j]);
                float s = (va[j] - VTH) > 0.f ? 1.f : 0.f;
                va[j] *= (1.f - s);
                cnt[j] += s;
                aplp += s * wk2a[j];
            }
            for (int off = 32; off > 0; off >>= 1) aplp += __shfl_xor(aplp, off, 64);
            if ((tid & 63) == 0) sRed[tid >> 6] = aplp;
        }
        __syncthreads();
        if (tid == 0) {
            float a = sRed[0] + sRed[1] + sRed[2] + sRed[3];
            sApl = fmaxf(a, 0.f);
        }
    }

    float acc[NOD];
#pragma unroll
    for (int o = 0; o < NOD; ++o) acc[o] = 0.f;
    if (act) {
#pragma unroll
        for (int j = 0; j < KPER; ++j) {
            float r = cnt[j] / 20.0f;
            if (r != 0.f) {
                const float* wr = dec_w + (long)(kbase + j) * NOD;
#pragma unroll
                for (int o = 0; o < NOD; ++o) acc[o] += r * wr[o];
            }
        }
    }
#pragma unroll
    for (int o = 0; o < NOD; ++o) {
        float v = acc[o];
        for (int off = 32; off > 0; off >>= 1) v += __shfl_xor(v, off, 64);
        if ((tid & 63) == 0) sRed2[(tid >> 6) * NOD + o] = v;
    }
    __syncthreads();
    if (tid < NOD) {
        float v = sRed2[tid] + sRed2[NOD + tid] + sRed2[2 * NOD + tid] +
                  sRed2[3 * NOD + tid] + dec_b[tid];
        out[(long)b * NOD + tid] = v;
    }
}

extern "C" void kernel_launch(void* const* d_in, const int* in_sizes, int n_in,
                              void* d_out, int out_size, void* d_ws, size_t ws_size,
                              hipStream_t stream) {
    (void)n_in; (void)out_size;
    const float* or_input  = (const float*)d_in[0];
    const float* or_gains  = (const float*)d_in[1];
    const float* mapping   = (const float*)d_in[2];
    const float* orn_to_pn = (const float*)d_in[3];
    const float* orn_to_ln = (const float*)d_in[4];
    const float* ln_to_pn  = (const float*)d_in[5];
    const float* pn_to_kc  = (const float*)d_in[6];
    const float* kc_to_apl = (const float*)d_in[7];
    const float* apl_to_kc = (const float*)d_in[8];
    const float* dec_w     = (const float*)d_in[9];
    const float* dec_b     = (const float*)d_in[10];
    float* out = (float*)d_out;

    const int batch = in_sizes[0] / NOR;  // 4096
    const size_t need = (size_t)batch * NSTEPS * sizeof(unsigned long long);

    if (ws_size >= need) {
        unsigned long long* g_masks = (unsigned long long*)d_ws;
        hipLaunchKernelGGL(phase1_kernel, dim3((batch + 3) / 4), dim3(TPB), 0, stream,
                           or_input, or_gains, mapping, orn_to_pn, orn_to_ln, ln_to_pn,
                           g_masks, batch);
        hipLaunchKernelGGL(phase2_kernel, dim3(batch), dim3(TPB), 0, stream,
                           g_masks, pn_to_kc, kc_to_apl, apl_to_kc, dec_w, dec_b, out);
    } else {
        hipLaunchKernelGGL(snn_fused, dim3(batch), dim3(TPB), 0, stream,
                           or_input, or_gains, mapping, orn_to_pn, orn_to_ln,
                           ln_to_pn, pn_to_kc, kc_to_apl, apl_to_kc, dec_w, dec_b, out);
    }
}